// Round 7
// baseline (197.287 us; speedup 1.0000x reference)
//
#include <hip/hip_runtime.h>

// Problem constants (B=2, C=64, C8=8, H=W=96 -> N=9216)
#define NTOK  9216
#define NBAT  2

typedef __attribute__((ext_vector_type(8))) short bf16x8;
typedef __attribute__((ext_vector_type(4))) float f32x4;
typedef __attribute__((ext_vector_type(4))) unsigned int u32x4;
typedef __attribute__((ext_vector_type(2))) unsigned int u32x2;

#if __has_builtin(__builtin_amdgcn_exp2f)
#define EXP2(x) __builtin_amdgcn_exp2f(x)
#else
#define EXP2(x) exp2f(x)
#endif
#define L2E 1.4426950408889634f

__device__ __forceinline__ unsigned short f2bf(float x) {
  unsigned int u = __builtin_bit_cast(unsigned int, x);
  u += 0x7fffu + ((u >> 16) & 1u);   // RNE
  return (unsigned short)(u >> 16);
}

// pack two non-negative floats to bf16x2 (round-half-up via +0x8000, v_perm)
__device__ __forceinline__ unsigned int pack_bf2(float lo, float hi) {
  unsigned int ulo = __builtin_bit_cast(unsigned int, lo) + 0x8000u;
  unsigned int uhi = __builtin_bit_cast(unsigned int, hi) + 0x8000u;
  return __builtin_amdgcn_perm(uhi, ulo, 0x07060302u);
}

// gfx950 cross-row register swaps.
__device__ __forceinline__ void pl32(unsigned int &a, unsigned int &b) {
#if __has_builtin(__builtin_amdgcn_permlane32_swap)
  u32x2 r = __builtin_amdgcn_permlane32_swap(a, b, false, false);
  a = r[0]; b = r[1];
#else
  asm("v_permlane32_swap_b32 %0, %1" : "+v"(a), "+v"(b));
#endif
}
__device__ __forceinline__ void pl16(unsigned int &a, unsigned int &b) {
#if __has_builtin(__builtin_amdgcn_permlane16_swap)
  u32x2 r = __builtin_amdgcn_permlane16_swap(a, b, false, false);
  a = r[0]; b = r[1];
#else
  asm("v_permlane16_swap_b32 %0, %1" : "+v"(a), "+v"(b));
#endif
}

// ---------------------------------------------------------------------------
// Kernel 1: QKV projections -> bf16 (V in j-tiled layout). (r4 form)
// ---------------------------------------------------------------------------
__global__ __launch_bounds__(256) void qkv_proj(
    const float* __restrict__ x,
    const float* __restrict__ Wq, const float* __restrict__ bq,
    const float* __restrict__ Wk, const float* __restrict__ bk,
    const float* __restrict__ Wv, const float* __restrict__ bv,
    unsigned short* __restrict__ qg, unsigned short* __restrict__ kg,
    unsigned short* __restrict__ vg)
{
  __shared__ __align__(16) float xl[64 * 68];
  const int bid = blockIdx.x;
  const int rg  = bid % 5;
  const int t2  = bid / 5;
  const int nt  = t2 % 144;
  const int b   = t2 / 144;
  const int t   = threadIdx.x;
  const int lane = t & 63;
  const int n0  = nt * 64;

  #pragma unroll
  for (int kk = 0; kk < 4; kk++) {
    int p = t + kk * 256;
    int c = p >> 4, n4 = (p & 15) << 2;
    *(float4*)(&xl[c * 68 + n4]) =
        *(const float4*)(x + (size_t)(b * 64 + c) * NTOK + n0 + n4);
  }
  __syncthreads();

  const int g  = __builtin_amdgcn_readfirstlane(t >> 6);  // wave id 0..3
  const int r0 = rg * 16 + g * 4;                         // rows r0..r0+3 (0..79)

  const float* wbase; const float* bias_p; int lr0;
  if (r0 < 8)       { wbase = Wq; bias_p = bq; lr0 = r0; }
  else if (r0 < 16) { wbase = Wk; bias_p = bk; lr0 = r0 - 8; }
  else              { wbase = Wv; bias_p = bv; lr0 = r0 - 16; }
  const float* w0 = wbase + lr0 * 64;

  float a0 = 0.f, a1 = 0.f, a2 = 0.f, a3 = 0.f;
  #pragma unroll 16
  for (int c = 0; c < 64; c++) {
    float xv = xl[c * 68 + lane];
    a0 = fmaf(w0[c],       xv, a0);
    a1 = fmaf(w0[64 + c],  xv, a1);
    a2 = fmaf(w0[128 + c], xv, a2);
    a3 = fmaf(w0[192 + c], xv, a3);
  }
  a0 += bias_p[lr0]; a1 += bias_p[lr0 + 1];
  a2 += bias_p[lr0 + 2]; a3 += bias_p[lr0 + 3];
  if (r0 < 8) { a0 *= L2E; a1 *= L2E; a2 *= L2E; a3 *= L2E; }  // wave-uniform

  const int n = n0 + lane;
  if (r0 < 16) {
    ushort4 o;
    o.x = f2bf(a0); o.y = f2bf(a1); o.z = f2bf(a2); o.w = f2bf(a3);
    unsigned short* dst = (r0 < 8) ? qg : kg;
    *(ushort4*)(dst + ((size_t)b * NTOK + n) * 8 + lr0) = o;
  } else {
    // tiled V store: vt[(b*144 + nt)][c][lane], c = lr0..lr0+3
    unsigned short* vt = vg + ((size_t)(b * 144 + nt) * 64) * 64;
    vt[(lr0    ) * 64 + lane] = f2bf(a0);
    vt[(lr0 + 1) * 64 + lane] = f2bf(a1);
    vt[(lr0 + 2) * 64 + lane] = f2bf(a2);
    vt[(lr0 + 3) * 64 + lane] = f2bf(a3);
  }
}

// ---------------------------------------------------------------------------
// Kernel 2: single-pass flash, 8-WAVE blocks (512 threads). Each block owns
// 32 q-rows and the full j range; 8 waves interleave j in 64-chunks with
// stride 512 -> 18 iters/wave (same per-wave latency profile as the best
// 102-us r4 config) but 16 resident waves/CU instead of 8: double the stall
// coverage at UNCHANGED per-wave register allocation. ITER body is
// byte-identical to r4's (compiler-scheduled, K double-banked, dense V).
// 3-level pairwise LDS merge (4 park, 4 add, 4-way final sum), 34816 B.
// ---------------------------------------------------------------------------

#define ITER(IT_, KFU_, KFP_)                                                 \
  {                                                                           \
    const int jp = jbase + ((IT_) << 9);                                      \
    const int jn = ((IT_) == 17) ? jbase : (jp + 512);                        \
    bf16x8 vf0[4], vf1[4];                                                    \
    _Pragma("unroll")                                                         \
    for (int ct = 0; ct < 4; ct++)                                            \
      vf0[ct] = *(const bf16x8*)(vb + (((size_t)(jp + ct * 16)) << 6) + vtoff); \
    _Pragma("unroll")                                                         \
    for (int ct = 0; ct < 4; ct++)                                            \
      vf1[ct] = *(const bf16x8*)(vb + (((size_t)(jp + ct * 16)) << 6) + vtoff + 32); \
    _Pragma("unroll")                                                         \
    for (int jt = 0; jt < 4; jt++)                                            \
      KFP_[jt] = *(const bf16x8*)(kb + ((jn) + jt * 16) * 8 + koff);          \
    unsigned int pw[2][8];                                                    \
    _Pragma("unroll")                                                         \
    for (int s = 0; s < 2; s++) {                                             \
      f32x4 st[4];                                                            \
      _Pragma("unroll")                                                       \
      for (int jt = 0; jt < 4; jt++)                                          \
        st[jt] = __builtin_amdgcn_mfma_f32_16x16x32_bf16(KFU_[jt], qf[s], z4, 0, 0, 0); \
      float ps = 0.f;                                                         \
      _Pragma("unroll")                                                       \
      for (int jt = 0; jt < 4; jt++) {                                        \
        float p0 = EXP2(st[jt][0]);                                           \
        float p1 = EXP2(st[jt][1]);                                           \
        float p2 = EXP2(st[jt][2]);                                           \
        float p3 = EXP2(st[jt][3]);                                           \
        ps += (p0 + p1) + (p2 + p3);                                          \
        pw[s][jt * 2]     = pack_bf2(p0, p1);                                 \
        pw[s][jt * 2 + 1] = pack_bf2(p2, p3);                                 \
      }                                                                       \
      if (s == 0) lp0 += ps; else lp1 += ps;                                  \
    }                                                                         \
    bf16x8 pf[2][2];                                                          \
    _Pragma("unroll")                                                         \
    for (int s = 0; s < 2; s++) {                                             \
      _Pragma("unroll")                                                       \
      for (int c = 0; c < 2; c++) {                                           \
        unsigned int a0 = pw[s][c * 4 + 0], a1 = pw[s][c * 4 + 1];            \
        unsigned int b0 = pw[s][c * 4 + 2], b1 = pw[s][c * 4 + 3];            \
        pl32(a0, b0); pl16(a0, b0);   /* a0 -> j=8q+{0,1}, b0 -> j=8q+{4,5} */ \
        pl32(a1, b1); pl16(a1, b1);   /* a1 -> j=8q+{2,3}, b1 -> j=8q+{6,7} */ \
        u32x4 f = {a0, a1, b0, b1};                                           \
        pf[s][c] = __builtin_bit_cast(bf16x8, f);                             \
      }                                                                       \
    }                                                                         \
    _Pragma("unroll")                                                         \
    for (int s = 0; s < 2; s++)                                               \
      _Pragma("unroll")                                                       \
      for (int ct = 0; ct < 4; ct++)                                          \
        acc[s][ct] = __builtin_amdgcn_mfma_f32_16x16x32_bf16(vf0[ct], pf[s][0], acc[s][ct], 0, 0, 0); \
    _Pragma("unroll")                                                         \
    for (int s = 0; s < 2; s++)                                               \
      _Pragma("unroll")                                                       \
      for (int ct = 0; ct < 4; ct++)                                          \
        acc[s][ct] = __builtin_amdgcn_mfma_f32_16x16x32_bf16(vf1[ct], pf[s][1], acc[s][ct], 0, 0, 0); \
  }

__global__ __launch_bounds__(512, 3) void flash_full(
    const unsigned short* __restrict__ qg,
    const unsigned short* __restrict__ kg,
    const unsigned short* __restrict__ vg,
    const float* __restrict__ x,
    const float* __restrict__ gamma_p, const float* __restrict__ dyn_p,
    float* __restrict__ y)
{
  __shared__ __align__(16) float obuf[4 * 2112];  // 4 tiles [64][33] = 33792 B
  __shared__ float l_s[8][32];

  const int bid  = blockIdx.x;          // b*288 + rt
  const int rt   = bid % 288;
  const int b    = bid / 288;
  const int tid  = threadIdx.x;
  const int w    = tid >> 6;            // wave 0..7
  const int lane = tid & 63;
  const int i16  = lane & 15;
  const int quad = lane >> 4;
  const int jbase = w << 6;             // waves interleave j, stride 512/iter

  const unsigned short* __restrict__ vb = vg + (size_t)b * 64 * NTOK; // tiled
  const unsigned short* __restrict__ kb = kg + (size_t)b * NTOK * 8;
  const int koff  = i16 * 8;
  const int vtoff = i16 * 64 + quad * 8;   // within a [c][64] j-tile slab

  bf16x8 qf[2] = {};
  if (quad == 0) {
    qf[0] = *(const bf16x8*)(qg + ((size_t)b * NTOK + rt * 32 + i16) * 8);
    qf[1] = *(const bf16x8*)(qg + ((size_t)b * NTOK + rt * 32 + 16 + i16) * 8);
  }

  f32x4 acc[2][4];
  #pragma unroll
  for (int s = 0; s < 2; s++)
    #pragma unroll
    for (int ct = 0; ct < 4; ct++) acc[s][ct] = (f32x4){0.f, 0.f, 0.f, 0.f};
  float lp0 = 0.f, lp1 = 0.f;
  const f32x4 z4 = {0.f, 0.f, 0.f, 0.f};

  bf16x8 kfA[4], kfB[4];
  #pragma unroll
  for (int jt = 0; jt < 4; jt++)
    kfA[jt] = *(const bf16x8*)(kb + (jbase + jt * 16) * 8 + koff);

  #pragma unroll 1
  for (int it2 = 0; it2 < 9; ++it2) {
    ITER(2 * it2,     kfA, kfB);
    ITER(2 * it2 + 1, kfB, kfA);
  }

  lp0 += __shfl_xor(lp0, 16); lp0 += __shfl_xor(lp0, 32);
  lp1 += __shfl_xor(lp1, 16); lp1 += __shfl_xor(lp1, 32);
  if (quad == 0) { l_s[w][i16] = lp0; l_s[w][16 + i16] = lp1; }

  // --- pairwise cross-wave reduction: waves 4-7 park, waves 0-3 add ---
  if (w >= 4) {
    float* dst = &obuf[(w - 4) * 2112];
    #pragma unroll
    for (int s = 0; s < 2; s++)
      #pragma unroll
      for (int ct = 0; ct < 4; ct++)
        #pragma unroll
        for (int r = 0; r < 4; r++)
          dst[(ct * 16 + quad * 4 + r) * 33 + s * 16 + i16] = acc[s][ct][r];
  }
  __syncthreads();
  if (w < 4) {
    float* t = &obuf[w * 2112];
    #pragma unroll
    for (int s = 0; s < 2; s++)
      #pragma unroll
      for (int ct = 0; ct < 4; ct++)
        #pragma unroll
        for (int r = 0; r < 4; r++) {
          int idx = (ct * 16 + quad * 4 + r) * 33 + s * 16 + i16;
          t[idx] += acc[s][ct][r];   // per-lane read-modify-write, bijective
        }
  }
  __syncthreads();

  // --- direct epilogue: y = gs*O/L + x ---
  const float gs = gamma_p[0] * dyn_p[0];
  #pragma unroll
  for (int e0 = 0; e0 < 4; e0++) {
    int e = tid + e0 * 512, c = e >> 5, r = e & 31;
    float L = (l_s[0][r] + l_s[1][r]) + (l_s[2][r] + l_s[3][r])
            + (l_s[4][r] + l_s[5][r]) + (l_s[6][r] + l_s[7][r]);
    float O = (obuf[c * 33 + r] + obuf[2112 + c * 33 + r])
            + (obuf[4224 + c * 33 + r] + obuf[6336 + c * 33 + r]);
    size_t a = (size_t)(b * 64 + c) * NTOK + rt * 32 + r;
    y[a] = gs * O / L + x[a];
  }
}

// ---------------------------------------------------------------------------
extern "C" void kernel_launch(void* const* d_in, const int* in_sizes, int n_in,
                              void* d_out, int out_size, void* d_ws, size_t ws_size,
                              hipStream_t stream) {
  const float* x     = (const float*)d_in[0];
  const float* Wq    = (const float*)d_in[1];
  const float* bq    = (const float*)d_in[2];
  const float* Wk    = (const float*)d_in[3];
  const float* bk    = (const float*)d_in[4];
  const float* Wv    = (const float*)d_in[5];
  const float* bv    = (const float*)d_in[6];
  const float* gamma = (const float*)d_in[7];
  const float* dyn   = (const float*)d_in[8];
  float* y = (float*)d_out;

  // workspace layout (bf16, 16B-aligned boundaries)
  unsigned short* qg = (unsigned short*)d_ws;              // B*N*8
  unsigned short* kg = qg + (size_t)NBAT * NTOK * 8;       // B*N*8
  unsigned short* vg = kg + (size_t)NBAT * NTOK * 8;       // B*64*N (tiled)

  qkv_proj<<<NBAT * 144 * 5, 256, 0, stream>>>(x, Wq, bq, Wk, bk, Wv, bv, qg, kg, vg);
  flash_full<<<NBAT * 288, 512, 0, stream>>>(qg, kg, vg, x, gamma, dyn, y);
}

// Round 8
// 136.394 us; speedup vs baseline: 1.4464x; 1.4464x over previous
//
#include <hip/hip_runtime.h>

// Problem constants (B=2, C=64, C8=8, H=W=96 -> N=9216)
#define NTOK  9216
#define NBAT  2

typedef __attribute__((ext_vector_type(8))) short bf16x8;
typedef __attribute__((ext_vector_type(4))) float f32x4;
typedef __attribute__((ext_vector_type(4))) unsigned int u32x4;
typedef __attribute__((ext_vector_type(2))) unsigned int u32x2;

#if __has_builtin(__builtin_amdgcn_exp2f)
#define EXP2(x) __builtin_amdgcn_exp2f(x)
#else
#define EXP2(x) exp2f(x)
#endif
#define L2E 1.4426950408889634f

__device__ __forceinline__ unsigned short f2bf(float x) {
  unsigned int u = __builtin_bit_cast(unsigned int, x);
  u += 0x7fffu + ((u >> 16) & 1u);   // RNE
  return (unsigned short)(u >> 16);
}

// pack two non-negative floats to bf16x2 (round-half-up via +0x8000, v_perm)
__device__ __forceinline__ unsigned int pack_bf2(float lo, float hi) {
  unsigned int ulo = __builtin_bit_cast(unsigned int, lo) + 0x8000u;
  unsigned int uhi = __builtin_bit_cast(unsigned int, hi) + 0x8000u;
  return __builtin_amdgcn_perm(uhi, ulo, 0x07060302u);
}

// gfx950 cross-row register swaps.
__device__ __forceinline__ void pl32(unsigned int &a, unsigned int &b) {
#if __has_builtin(__builtin_amdgcn_permlane32_swap)
  u32x2 r = __builtin_amdgcn_permlane32_swap(a, b, false, false);
  a = r[0]; b = r[1];
#else
  asm("v_permlane32_swap_b32 %0, %1" : "+v"(a), "+v"(b));
#endif
}
__device__ __forceinline__ void pl16(unsigned int &a, unsigned int &b) {
#if __has_builtin(__builtin_amdgcn_permlane16_swap)
  u32x2 r = __builtin_amdgcn_permlane16_swap(a, b, false, false);
  a = r[0]; b = r[1];
#else
  asm("v_permlane16_swap_b32 %0, %1" : "+v"(a), "+v"(b));
#endif
}

// ---------------------------------------------------------------------------
// Kernel 1: QKV projections -> bf16 (V in j-tiled layout). (r4 form)
// ---------------------------------------------------------------------------
__global__ __launch_bounds__(256) void qkv_proj(
    const float* __restrict__ x,
    const float* __restrict__ Wq, const float* __restrict__ bq,
    const float* __restrict__ Wk, const float* __restrict__ bk,
    const float* __restrict__ Wv, const float* __restrict__ bv,
    unsigned short* __restrict__ qg, unsigned short* __restrict__ kg,
    unsigned short* __restrict__ vg)
{
  __shared__ __align__(16) float xl[64 * 68];
  const int bid = blockIdx.x;
  const int rg  = bid % 5;
  const int t2  = bid / 5;
  const int nt  = t2 % 144;
  const int b   = t2 / 144;
  const int t   = threadIdx.x;
  const int lane = t & 63;
  const int n0  = nt * 64;

  #pragma unroll
  for (int kk = 0; kk < 4; kk++) {
    int p = t + kk * 256;
    int c = p >> 4, n4 = (p & 15) << 2;
    *(float4*)(&xl[c * 68 + n4]) =
        *(const float4*)(x + (size_t)(b * 64 + c) * NTOK + n0 + n4);
  }
  __syncthreads();

  const int g  = __builtin_amdgcn_readfirstlane(t >> 6);  // wave id 0..3
  const int r0 = rg * 16 + g * 4;                         // rows r0..r0+3 (0..79)

  const float* wbase; const float* bias_p; int lr0;
  if (r0 < 8)       { wbase = Wq; bias_p = bq; lr0 = r0; }
  else if (r0 < 16) { wbase = Wk; bias_p = bk; lr0 = r0 - 8; }
  else              { wbase = Wv; bias_p = bv; lr0 = r0 - 16; }
  const float* w0 = wbase + lr0 * 64;

  float a0 = 0.f, a1 = 0.f, a2 = 0.f, a3 = 0.f;
  #pragma unroll 16
  for (int c = 0; c < 64; c++) {
    float xv = xl[c * 68 + lane];
    a0 = fmaf(w0[c],       xv, a0);
    a1 = fmaf(w0[64 + c],  xv, a1);
    a2 = fmaf(w0[128 + c], xv, a2);
    a3 = fmaf(w0[192 + c], xv, a3);
  }
  a0 += bias_p[lr0]; a1 += bias_p[lr0 + 1];
  a2 += bias_p[lr0 + 2]; a3 += bias_p[lr0 + 3];
  if (r0 < 8) { a0 *= L2E; a1 *= L2E; a2 *= L2E; a3 *= L2E; }  // wave-uniform

  const int n = n0 + lane;
  if (r0 < 16) {
    ushort4 o;
    o.x = f2bf(a0); o.y = f2bf(a1); o.z = f2bf(a2); o.w = f2bf(a3);
    unsigned short* dst = (r0 < 8) ? qg : kg;
    *(ushort4*)(dst + ((size_t)b * NTOK + n) * 8 + lr0) = o;
  } else {
    // tiled V store: vt[(b*144 + nt)][c][lane], c = lr0..lr0+3
    unsigned short* vt = vg + ((size_t)(b * 144 + nt) * 64) * 64;
    vt[(lr0    ) * 64 + lane] = f2bf(a0);
    vt[(lr0 + 1) * 64 + lane] = f2bf(a1);
    vt[(lr0 + 2) * 64 + lane] = f2bf(a2);
    vt[(lr0 + 3) * 64 + lane] = f2bf(a3);
  }
}

// ---------------------------------------------------------------------------
// Kernel 2: single-pass flash, LEAN j-32 iterations. r8: per-iter register
// state minimized (no K/V double banks, one V half-tile, one pf per s) so
// unified VGPR+acc demand drops below the 128-reg allocation quantum ->
// 3+ blocks/CU become legal (the 2-waves/SIMD cap of r0-r7 was the >128
// bucket). 36 iters of j-32; waves interleave 64-j slabs at stride 256,
// alternating low/high 32 within a slab. 576 blocks @ 3/CU = zero tail.
// ---------------------------------------------------------------------------
__global__ __launch_bounds__(256, 3) void flash_full(
    const unsigned short* __restrict__ qg,
    const unsigned short* __restrict__ kg,
    const unsigned short* __restrict__ vg,
    const float* __restrict__ x,
    const float* __restrict__ gamma_p, const float* __restrict__ dyn_p,
    float* __restrict__ y)
{
  __shared__ __align__(16) float obuf[2 * 2112];  // 2 tiles [64][33] = 16896 B
  __shared__ float l_s[4][32];

  const int bid  = blockIdx.x;          // b*288 + rt
  const int rt   = bid % 288;
  const int b    = bid / 288;
  const int tid  = threadIdx.x;
  const int w    = tid >> 6;
  const int lane = tid & 63;
  const int i16  = lane & 15;
  const int quad = lane >> 4;
  const int jbase = w << 6;             // 64-j slabs, stride 256 across waves

  const unsigned short* __restrict__ vb = vg + (size_t)b * 64 * NTOK; // tiled
  const unsigned short* __restrict__ kb = kg + (size_t)b * NTOK * 8;
  const int koff  = i16 * 8;
  const int vtoff = i16 * 64 + quad * 8;   // within a [c][64] j-tile slab

  bf16x8 qf[2] = {};
  if (quad == 0) {
    qf[0] = *(const bf16x8*)(qg + ((size_t)b * NTOK + rt * 32 + i16) * 8);
    qf[1] = *(const bf16x8*)(qg + ((size_t)b * NTOK + rt * 32 + 16 + i16) * 8);
  }

  f32x4 acc[2][4];
  #pragma unroll
  for (int s = 0; s < 2; s++)
    #pragma unroll
    for (int ct = 0; ct < 4; ct++) acc[s][ct] = (f32x4){0.f, 0.f, 0.f, 0.f};
  float lp0 = 0.f, lp1 = 0.f;
  const f32x4 z4 = {0.f, 0.f, 0.f, 0.f};

  #pragma unroll 1
  for (int it = 0; it < 36; ++it) {
    const int jp  = jbase + ((it >> 1) << 8);   // 64-aligned slab base
    const int jlo = (it & 1) << 5;              // 0 | 32 within slab

    bf16x8 vf[4];
    #pragma unroll
    for (int ct = 0; ct < 4; ct++)
      vf[ct] = *(const bf16x8*)(vb + (((size_t)(jp + ct * 16)) << 6) + vtoff + jlo);
    bf16x8 kf[2];
    #pragma unroll
    for (int jt = 0; jt < 2; jt++)
      kf[jt] = *(const bf16x8*)(kb + (jp + jlo + jt * 16) * 8 + koff);

    unsigned int pw[2][4];
    #pragma unroll
    for (int s = 0; s < 2; s++) {
      f32x4 st[2];
      #pragma unroll
      for (int jt = 0; jt < 2; jt++)
        st[jt] = __builtin_amdgcn_mfma_f32_16x16x32_bf16(kf[jt], qf[s], z4, 0, 0, 0);
      float ps = 0.f;
      #pragma unroll
      for (int jt = 0; jt < 2; jt++) {
        float p0 = EXP2(st[jt][0]);
        float p1 = EXP2(st[jt][1]);
        float p2 = EXP2(st[jt][2]);
        float p3 = EXP2(st[jt][3]);
        ps += (p0 + p1) + (p2 + p3);
        pw[s][jt * 2]     = pack_bf2(p0, p1);
        pw[s][jt * 2 + 1] = pack_bf2(p2, p3);
      }
      if (s == 0) lp0 += ps; else lp1 += ps;
    }

    #pragma unroll
    for (int s = 0; s < 2; s++) {
      unsigned int a0 = pw[s][0], a1 = pw[s][1];
      unsigned int b0 = pw[s][2], b1 = pw[s][3];
      pl32(a0, b0); pl16(a0, b0);   // a0 -> j=8q+{0,1}, b0 -> j=8q+{4,5}
      pl32(a1, b1); pl16(a1, b1);   // a1 -> j=8q+{2,3}, b1 -> j=8q+{6,7}
      u32x4 f = {a0, a1, b0, b1};
      bf16x8 pf = __builtin_bit_cast(bf16x8, f);
      #pragma unroll
      for (int ct = 0; ct < 4; ct++)
        acc[s][ct] = __builtin_amdgcn_mfma_f32_16x16x32_bf16(vf[ct], pf, acc[s][ct], 0, 0, 0);
    }
  }

  lp0 += __shfl_xor(lp0, 16); lp0 += __shfl_xor(lp0, 32);
  lp1 += __shfl_xor(lp1, 16); lp1 += __shfl_xor(lp1, 32);
  if (quad == 0) { l_s[w][i16] = lp0; l_s[w][16 + i16] = lp1; }

  // --- two-pass cross-wave reduction: only 2 tiles live in LDS at a time ---
  if (w >= 2) {
    float* dst = &obuf[(w - 2) * 2112];
    #pragma unroll
    for (int s = 0; s < 2; s++)
      #pragma unroll
      for (int ct = 0; ct < 4; ct++)
        #pragma unroll
        for (int r = 0; r < 4; r++)
          dst[(ct * 16 + quad * 4 + r) * 33 + s * 16 + i16] = acc[s][ct][r];
  }
  __syncthreads();
  if (w < 2) {
    float* t = &obuf[w * 2112];
    #pragma unroll
    for (int s = 0; s < 2; s++)
      #pragma unroll
      for (int ct = 0; ct < 4; ct++)
        #pragma unroll
        for (int r = 0; r < 4; r++) {
          int idx = (ct * 16 + quad * 4 + r) * 33 + s * 16 + i16;
          t[idx] += acc[s][ct][r];   // per-lane read-modify-write, bijective
        }
  }
  __syncthreads();

  // --- direct epilogue: y = gs*O/L + x ---
  const float gs = gamma_p[0] * dyn_p[0];
  #pragma unroll
  for (int e0 = 0; e0 < 8; e0++) {
    int e = tid + e0 * 256, c = e >> 5, r = e & 31;
    float L = (l_s[0][r] + l_s[1][r]) + (l_s[2][r] + l_s[3][r]);
    float O = obuf[c * 33 + r] + obuf[2112 + c * 33 + r];
    size_t a = (size_t)(b * 64 + c) * NTOK + rt * 32 + r;
    y[a] = gs * O / L + x[a];
  }
}

// ---------------------------------------------------------------------------
extern "C" void kernel_launch(void* const* d_in, const int* in_sizes, int n_in,
                              void* d_out, int out_size, void* d_ws, size_t ws_size,
                              hipStream_t stream) {
  const float* x     = (const float*)d_in[0];
  const float* Wq    = (const float*)d_in[1];
  const float* bq    = (const float*)d_in[2];
  const float* Wk    = (const float*)d_in[3];
  const float* bk    = (const float*)d_in[4];
  const float* Wv    = (const float*)d_in[5];
  const float* bv    = (const float*)d_in[6];
  const float* gamma = (const float*)d_in[7];
  const float* dyn   = (const float*)d_in[8];
  float* y = (float*)d_out;

  // workspace layout (bf16, 16B-aligned boundaries)
  unsigned short* qg = (unsigned short*)d_ws;              // B*N*8
  unsigned short* kg = qg + (size_t)NBAT * NTOK * 8;       // B*N*8
  unsigned short* vg = kg + (size_t)NBAT * NTOK * 8;       // B*64*N (tiled)

  qkv_proj<<<NBAT * 144 * 5, 256, 0, stream>>>(x, Wq, bq, Wk, bk, Wv, bv, qg, kg, vg);
  flash_full<<<NBAT * 288, 256, 0, stream>>>(qg, kg, vg, x, gamma, dyn, y);
}